// Round 4
// baseline (2014.633 us; speedup 1.0000x reference)
//
#include <hip/hip_runtime.h>

typedef __bf16 bf16;
typedef _Float16 f16;
typedef f16 f16x8 __attribute__((ext_vector_type(8)));
typedef float f32x4 __attribute__((ext_vector_type(4)));

__device__ __forceinline__ f32x4 mfma16h(f16x8 a, f16x8 b, f32x4 c) {
  return __builtin_amdgcn_mfma_f32_16x16x32_f16(a, b, c, 0, 0, 0);
}
__device__ __forceinline__ float sigm(float x) { return 1.0f / (1.0f + __expf(-x)); }
__device__ __forceinline__ float tanh_f(float x) {
  float e = __expf(-2.0f * fabsf(x));
  return copysignf((1.0f - e) / (1.0f + e), x);
}
__device__ __forceinline__ float ldin(const void* p, long i, int f32m) {
  if (f32m) return ((const float*)p)[i];
  unsigned u = (unsigned)((const unsigned short*)p)[i] << 16;
  return __uint_as_float(u);
}
__device__ __forceinline__ unsigned short f16u(f16 h) { return __builtin_bit_cast(unsigned short, h); }
__device__ __forceinline__ float bfc(unsigned short s) { return __uint_as_float((unsigned)s << 16); }

// ---------------- dtype detection ----------------
__global__ void detect_dtype(const unsigned short* __restrict__ p, int* __restrict__ flag) {
  __shared__ int cnt;
  if (threadIdx.x == 0) cnt = 0;
  __syncthreads();
  int c = 0;
  for (int i = threadIdx.x; i < 4096; i += 256) {
    unsigned e = (p[2 * i] >> 7) & 0xFFu;
    if (e >= 0xC0u) ++c;
  }
  atomicAdd(&cnt, c);
  __syncthreads();
  if (threadIdx.x == 0) *flag = (cnt > 64) ? 1 : 0;
}

// ---------------- converters: all weights -> single fp16 (one kernel) ----------------
// wAll (f16) element offsets:
//   padded tri Wih: table below                    total 245760
//   tri Whh: 245760 + md*16384                     total 98304
//   r_Wih: 344064 + c*65536   r_Whh: 606208 + c*65536
//   dWihF: 868352  dWhhF: 933888  dWihB: 999424  dWhhB: 1064960   end 1130496
// fmisc float offsets: tri bias md*256; r_b 1536; d_b_f 3584; d_b_b 4096;
//   uscW 4608+mk*16384; fc1W 201216; fc1b 209408; fc2W 209472; fc2b 209536

struct PadArgs { const void* src[6]; };
struct HiloArgs { const void* src[12]; int n[12]; int off[12]; };
struct F32Args { const void* src[16]; int n[16]; int off[16]; };

__global__ void conv_all(PadArgs pa, HiloArgs ha, F32Args fa,
                         f16* __restrict__ wo, float* __restrict__ fm,
                         const int* __restrict__ flag) {
  const int y = blockIdx.y;
  const int f32m = *flag;
  if (y < 6) {
    const int dinT[6] = {300, 300, 74, 74, 35, 35};
    const int kpT[6] = {320, 320, 96, 96, 64, 64};
    const int offT[6] = {0, 81920, 163840, 188416, 212992, 229376};
    int din = dinT[y], kp = kpT[y];
    const void* s = pa.src[y];
    f16* o = wo + offT[y];
    int total = 256 * kp;
    for (int i = blockIdx.x * blockDim.x + threadIdx.x; i < total; i += gridDim.x * blockDim.x) {
      int n = i / kp, k = i - n * kp;
      float v = (k < din) ? ldin(s, n * din + k, f32m) : 0.0f;
      o[i] = (f16)v;
    }
  } else if (y < 18) {
    int j = y - 6;
    int n = ha.n[j];
    const void* s = ha.src[j];
    f16* o = wo + ha.off[j];
    for (int i = blockIdx.x * blockDim.x + threadIdx.x; i < n; i += gridDim.x * blockDim.x)
      o[i] = (f16)ldin(s, i, f32m);
  } else {
    int j = y - 18;
    int n = fa.n[j];
    const void* s = fa.src[j];
    float* d = fm + fa.off[j];
    for (int i = blockIdx.x * blockDim.x + threadIdx.x; i < n; i += gridDim.x * blockDim.x)
      d[i] = ldin(s, i, f32m);
  }
}

// ---------------- fused trimodal bidirectional LSTMs (fp16 MFMA) ----------------
struct TriArgs {
  const void* x[3];
  const f16* wAll;
  const float* fmisc;
  float* ctx;
  const int* flag;
};

template <int DIN, int KP, int CHUNK, int F32M>
__device__ void tri_body(const void* __restrict__ xsrc,
                         const f16* __restrict__ wp, const f16* __restrict__ whh,
                         const float* __restrict__ bias, float* __restrict__ ctx,
                         int m, int d, int b0, char* sm) {
  constexpr int XP = KP + 8;
  constexpr int NKS = KP / 32;
  constexpr int NCH = DIN / CHUNK;
  constexpr int ITER = (NCH + 15) / 16;

  f16 (*Xhi)[XP] = (f16 (*)[XP])sm;
  f16 (*Xlo)[XP] = (f16 (*)[XP])(sm + 32 * XP * 2);
  f16 (*hbuf)[16][72] = (f16 (*)[16][72])(sm + 64 * XP * 2);
  float* gbuf = (float*)(sm + 64 * XP * 2 + 4608);  // [16][260] f32

  const int tid = threadIdx.x;
  const int lane = tid & 63, n16 = lane & 15, q = lane >> 4, w8 = tid >> 6;
  const int srow = tid & 31, sct = tid >> 5;
  const int hc = tid & 63, rr = tid >> 6;

  f16x8 wihr[2][NKS];
  f16x8 whr[2][2];
#pragma unroll
  for (int t = 0; t < 2; ++t) {
    int cc = (w8 + t * 8) * 16 + n16;
#pragma unroll
    for (int ks = 0; ks < NKS; ++ks)
      wihr[t][ks] = *(const f16x8*)(wp + cc * KP + ks * 32 + q * 8);
#pragma unroll
    for (int ks = 0; ks < 2; ++ks)
      whr[t][ks] = *(const f16x8*)(whh + cc * 64 + ks * 32 + q * 8);
  }
  float bgm[4];
#pragma unroll
  for (int g = 0; g < 4; ++g) bgm[g] = bias[g * 64 + hc];

  {
    unsigned* z = (unsigned*)sm;
    int nz = (64 * XP * 2 + 4608) >> 2;
    for (int i = tid; i < nz; i += 512) z[i] = 0u;
  }

  uint4 pf[ITER];
  auto stage_load = [&](int tg) {
#pragma unroll
    for (int i = 0; i < ITER; ++i) {
      int c = sct + i * 16;
      if (c < NCH) {
        int tl = srow >> 4, bb = srow & 15;
        int t = tg * 2 + tl; if (d) t = 127 - t;
        long base = ((long)(b0 + bb) * 128 + t) * DIN + c * CHUNK;
        if (F32M) {
          const float* p = (const float*)xsrc + base;
          if constexpr (CHUNK == 4) pf[i] = *(const uint4*)p;
          else if constexpr (CHUNK == 2) { uint2 v = *(const uint2*)p; pf[i].x = v.x; pf[i].y = v.y; }
          else pf[i].x = *(const unsigned*)p;
        } else {
          const unsigned short* p = (const unsigned short*)xsrc + base;
          if constexpr (CHUNK == 4) { uint2 v = *(const uint2*)p; pf[i].x = v.x; pf[i].y = v.y; }
          else if constexpr (CHUNK == 2) pf[i].x = *(const unsigned*)p;
          else pf[i].x = *p;
        }
      }
    }
  };
  auto stage_store = [&]() {
#pragma unroll
    for (int i = 0; i < ITER; ++i) {
      int c = sct + i * 16;
      if (c < NCH) {
        float v[4];
        if (F32M) {
          v[0] = __uint_as_float(pf[i].x); v[1] = __uint_as_float(pf[i].y);
          v[2] = __uint_as_float(pf[i].z); v[3] = __uint_as_float(pf[i].w);
        } else {
          v[0] = bfc((unsigned short)(pf[i].x & 0xFFFF));
          v[1] = bfc((unsigned short)(pf[i].x >> 16));
          v[2] = bfc((unsigned short)(pf[i].y & 0xFFFF));
          v[3] = bfc((unsigned short)(pf[i].y >> 16));
        }
        unsigned short hb[4], lb[4];
#pragma unroll
        for (int e = 0; e < CHUNK; ++e) {
          f16 h = (f16)v[e];
          hb[e] = f16u(h);
          lb[e] = f16u((f16)(v[e] - (float)h));
        }
        if constexpr (CHUNK == 4) {
          uint2 H; H.x = hb[0] | ((unsigned)hb[1] << 16); H.y = hb[2] | ((unsigned)hb[3] << 16);
          *(uint2*)&Xhi[srow][c * 4] = H;
          if (F32M) {
            uint2 L; L.x = lb[0] | ((unsigned)lb[1] << 16); L.y = lb[2] | ((unsigned)lb[3] << 16);
            *(uint2*)&Xlo[srow][c * 4] = L;
          }
        } else if constexpr (CHUNK == 2) {
          *(unsigned*)&Xhi[srow][c * 2] = hb[0] | ((unsigned)hb[1] << 16);
          if (F32M) *(unsigned*)&Xlo[srow][c * 2] = lb[0] | ((unsigned)lb[1] << 16);
        } else {
          *(unsigned short*)&Xhi[srow][c] = hb[0];
          if (F32M) *(unsigned short*)&Xlo[srow][c] = lb[0];
        }
      }
    }
  };

  float c2[2] = {0.f, 0.f};
  stage_load(0);
  __syncthreads();

  for (int tg = 0; tg < 64; ++tg) {
    stage_store();
    if (tg < 63) stage_load(tg + 1);
    __syncthreads();

    f32x4 a00, a01, a10, a11;
    {
      const f32x4 zf = {0.f, 0.f, 0.f, 0.f};
      a00 = zf; a01 = zf; a10 = zf; a11 = zf;
    }
#pragma unroll
    for (int ks = 0; ks < NKS; ++ks) {
      f16x8 ah0 = *(const f16x8*)(&Xhi[n16][ks * 32 + q * 8]);
      f16x8 ah1 = *(const f16x8*)(&Xhi[16 + n16][ks * 32 + q * 8]);
      a00 = mfma16h(ah0, wihr[0][ks], a00);
      a01 = mfma16h(ah0, wihr[1][ks], a01);
      a10 = mfma16h(ah1, wihr[0][ks], a10);
      a11 = mfma16h(ah1, wihr[1][ks], a11);
      if (F32M) {
        f16x8 al0 = *(const f16x8*)(&Xlo[n16][ks * 32 + q * 8]);
        f16x8 al1 = *(const f16x8*)(&Xlo[16 + n16][ks * 32 + q * 8]);
        a00 = mfma16h(al0, wihr[0][ks], a00);
        a01 = mfma16h(al0, wihr[1][ks], a01);
        a10 = mfma16h(al1, wihr[0][ks], a10);
        a11 = mfma16h(al1, wihr[1][ks], a11);
      }
    }

    {
      f16x8 h0 = *(const f16x8*)(&hbuf[0][n16][q * 8]);
      f16x8 h1 = *(const f16x8*)(&hbuf[0][n16][32 + q * 8]);
      a00 = mfma16h(h0, whr[0][0], a00); a00 = mfma16h(h1, whr[0][1], a00);
      a01 = mfma16h(h0, whr[1][0], a01); a01 = mfma16h(h1, whr[1][1], a01);
    }
#pragma unroll
    for (int e = 0; e < 4; ++e) {
      gbuf[(q * 4 + e) * 260 + w8 * 16 + n16] = a00[e];
      gbuf[(q * 4 + e) * 260 + 128 + w8 * 16 + n16] = a01[e];
    }
    __syncthreads();

#pragma unroll
    for (int e = 0; e < 2; ++e) {
      int row = rr + e * 8;
      float gi = gbuf[row * 260 + hc] + bgm[0];
      float gf = gbuf[row * 260 + 64 + hc] + bgm[1];
      float gg = gbuf[row * 260 + 128 + hc] + bgm[2];
      float go = gbuf[row * 260 + 192 + hc] + bgm[3];
      float c = sigm(gf) * c2[e] + sigm(gi) * tanh_f(gg);
      c2[e] = c;
      float h = sigm(go) * tanh_f(c);
      hbuf[1][row][hc] = (f16)h;
    }
    __syncthreads();

    {
      f16x8 h0 = *(const f16x8*)(&hbuf[1][n16][q * 8]);
      f16x8 h1 = *(const f16x8*)(&hbuf[1][n16][32 + q * 8]);
      a10 = mfma16h(h0, whr[0][0], a10); a10 = mfma16h(h1, whr[0][1], a10);
      a11 = mfma16h(h0, whr[1][0], a11); a11 = mfma16h(h1, whr[1][1], a11);
    }
#pragma unroll
    for (int e = 0; e < 4; ++e) {
      gbuf[(q * 4 + e) * 260 + w8 * 16 + n16] = a10[e];
      gbuf[(q * 4 + e) * 260 + 128 + w8 * 16 + n16] = a11[e];
    }
    __syncthreads();

    const bool lastStep = (tg == 63);
#pragma unroll
    for (int e = 0; e < 2; ++e) {
      int row = rr + e * 8;
      float gi = gbuf[row * 260 + hc] + bgm[0];
      float gf = gbuf[row * 260 + 64 + hc] + bgm[1];
      float gg = gbuf[row * 260 + 128 + hc] + bgm[2];
      float go = gbuf[row * 260 + 192 + hc] + bgm[3];
      float c = sigm(gf) * c2[e] + sigm(gi) * tanh_f(gg);
      c2[e] = c;
      float h = sigm(go) * tanh_f(c);
      hbuf[0][row][hc] = (f16)h;
      if (lastStep) ctx[(m * 1024 + b0 + row) * 128 + d * 64 + hc] = h;
    }
  }
}

__global__ __launch_bounds__(512, 2) void tri_lstm(TriArgs A) {
  __shared__ __align__(16) char sm[64 * 328 * 2 + 4608 + 16640];
  int bid = blockIdx.x;
  int md = bid >> 6, xb = bid & 63;
  int m = md >> 1, d = md & 1, b0 = xb * 16;
  const int wpOffT[6] = {0, 81920, 163840, 188416, 212992, 229376};
  const f16* wp = A.wAll + wpOffT[md];
  const f16* whh = A.wAll + 245760 + md * 16384;
  const float* bias = A.fmisc + md * 256;
  int f32m = *A.flag;
  if (f32m) {
    if (m == 0)      tri_body<300, 320, 4, 1>(A.x[0], wp, whh, bias, A.ctx, m, d, b0, sm);
    else if (m == 1) tri_body<74, 96, 2, 1>(A.x[1], wp, whh, bias, A.ctx, m, d, b0, sm);
    else             tri_body<35, 64, 1, 1>(A.x[2], wp, whh, bias, A.ctx, m, d, b0, sm);
  } else {
    if (m == 0)      tri_body<300, 320, 4, 0>(A.x[0], wp, whh, bias, A.ctx, m, d, b0, sm);
    else if (m == 1) tri_body<74, 96, 2, 0>(A.x[1], wp, whh, bias, A.ctx, m, d, b0, sm);
    else             tri_body<35, 64, 1, 0>(A.x[2], wp, whh, bias, A.ctx, m, d, b0, sm);
  }
}

// ---------------- fused routing phase v2 ----------------
// One block per 16-row batch tile. Inside: usc prologue (verbatim math from
// usc_kern), then 4 rounds of {4 chains in PARALLEL on 128-thread groups,
// 2 decision dirs in PARALLEL on 256-thread groups, update}, head epilogue
// (verbatim math from head). Staging inputs are prefetched to registers one
// step ahead. Single-buffered X/h with 2 barriers per step. dcF/dcB/bcg/usc
// per-tile rows in global (same-CU store->load, validated in prior rounds).
__global__ __launch_bounds__(512, 2) void routing(
    const float* __restrict__ ctx, float* __restrict__ usc,
    const f16* __restrict__ wAll, const float* __restrict__ fmisc,
    float* __restrict__ bcg, float* __restrict__ dcF, float* __restrict__ dcB,
    void* __restrict__ out, const int* __restrict__ flag) {
  __shared__ __align__(16) char smr[54784];
  float (*rcsS)[16] = (float (*)[16])(smr + 52224);
  float (*rclS)[16][4] = (float (*)[16][4])(smr + 53248);
  float (*rclD)[8] = (float (*)[8])(smr + 54272);

  const int tid = threadIdx.x;
  const int lane = tid & 63, n16 = lane & 15, q = lane >> 4;
  const int b0 = blockIdx.x * 16;

  const int WihOff[4] = {344064, 409600, 475136, 540672};
  const int WhhOff[4] = {606208, 671744, 737280, 802816};
  const int bOff[4] = {1536, 2048, 2560, 3072};
  const int preMk0[4] = {0, 1, 5, 2};
  const int preMk1[4] = {4, 8, 9, 6};
  const int dmk[3] = {3, 7, 11};
  const int WihOffD[2] = {868352, 999424};
  const int WhhOffD[2] = {933888, 1064960};
  const int bOffD[2] = {3584, 4096};

  // ---------- phase 0: usc for this tile (order-identical to usc_kern) ----------
  {
    float (*crS)[16][128] = (float (*)[16][128])smr;
    for (int i = tid; i < 3 * 16 * 128; i += 512) {
      int mod = i >> 11, rw = (i >> 7) & 15, dd = i & 127;
      crS[mod][rw][dd] = ctx[(mod * 1024 + b0 + rw) * 128 + dd];
    }
    __syncthreads();
    int e = tid & 127, rg = tid >> 7;
    for (int mk = 0; mk < 12; ++mk) {
      const float* W = fmisc + 4608 + mk * 16384;
      int mod = mk >> 2;
      float a0 = 0.f, a1 = 0.f, a2 = 0.f, a3 = 0.f;
      for (int dd = 0; dd < 128; ++dd) {
        float wv = W[dd * 128 + e];
        a0 += crS[mod][rg * 4 + 0][dd] * wv;
        a1 += crS[mod][rg * 4 + 1][dd] * wv;
        a2 += crS[mod][rg * 4 + 2][dd] * wv;
        a3 += crS[mod][rg * 4 + 3][dd] * wv;
      }
      usc[(mk * 1024 + b0 + rg * 4 + 0) * 128 + e] = a0;
      usc[(mk * 1024 + b0 + rg * 4 + 1) * 128 + e] = a1;
      usc[(mk * 1024 + b0 + rg * 4 + 2) * 128 + e] = a2;
      usc[(mk * 1024 + b0 + rg * 4 + 3) * 128 + e] = a3;
    }
  }
  if (tid < 256) rcsS[tid >> 4][tid & 15] = 1.0f;

  for (int r = 0; r < 4; ++r) {
    // ===== 4 chains in parallel (128-thread groups) =====
    {
      const int ch = tid >> 7, lt = tid & 127, w2 = (tid >> 6) & 1;
      const int ns = (ch == 3) ? 3 : 2;
      __syncthreads();  // usc/rcsS writes visible; buffers free
      if (lt < 16) {
        int row = lt;
        int goff = (ch == 3) ? 6 : ch * 2;
        float v[3], mx = -1e30f;
        for (int j = 0; j < ns; ++j) { v[j] = rcsS[row][goff + j]; mx = fmaxf(mx, v[j]); }
        float s = 0.f;
        for (int j = 0; j < ns; ++j) { v[j] = __expf(v[j] - mx); s += v[j]; }
        float inv = 1.0f / s;
        for (int j = 0; j < ns; ++j) rclS[ch][row][j] = v[j] * inv;
      }
      char* cb = smr + ch * 13056;
      f16 (*xh_c)[136] = (f16 (*)[136])cb;
      f16 (*xl_c)[136] = (f16 (*)[136])(cb + 4352);
      f16 (*hh_c)[136] = (f16 (*)[136])(cb + 8704);
      for (int i = lt; i < 16 * 136; i += 128) (&hh_c[0][0])[i] = (f16)0.0f;

      const f16* Wih = wAll + WihOff[ch];
      const f16* Whh = wAll + WhhOff[ch];
      float bgm[4][4];
#pragma unroll
      for (int g = 0; g < 4; ++g)
#pragma unroll
        for (int cc = 0; cc < 4; ++cc)
          bgm[g][cc] = fmisc[bOff[ch] + g * 128 + cc * 32 + w2 * 16 + n16];
      float creg[4][4];
#pragma unroll
      for (int e = 0; e < 4; ++e)
#pragma unroll
        for (int cc = 0; cc < 4; ++cc) creg[e][cc] = 0.f;

      float pf[16];
      {
        int mk0 = preMk0[ch];
#pragma unroll
        for (int rw = 0; rw < 16; ++rw)
          pf[rw] = usc[(mk0 * 1024 + b0 + rw) * 128 + lt];
      }
      __syncthreads();  // rclS + hh zero visible

      for (int s = 0; s < 3; ++s) {
        const bool act = s < ns;
        if (act) {
#pragma unroll
          for (int rw = 0; rw < 16; ++rw) {
            float xv = rclS[ch][rw][s] * pf[rw];
            f16 xhv = (f16)xv;
            xh_c[rw][lt] = xhv;
            xl_c[rw][lt] = (f16)(xv - (float)xhv);
          }
          if (s + 1 < ns) {
            int mk2 = (s + 1 == 1) ? preMk1[ch] : 10;
#pragma unroll
            for (int rw = 0; rw < 16; ++rw)
              pf[rw] = usc[(mk2 * 1024 + b0 + rw) * 128 + lt];
          }
        }
        __syncthreads();  // staged X visible; prev gate writes visible
        f32x4 acc[4][4];
        if (act) {
          const f32x4 zf = {0.f, 0.f, 0.f, 0.f};
#pragma unroll
          for (int g = 0; g < 4; ++g)
#pragma unroll
            for (int cc = 0; cc < 4; ++cc) acc[g][cc] = zf;
#pragma unroll
          for (int ks = 0; ks < 4; ++ks) {
            f16x8 axh = *(const f16x8*)(&xh_c[n16][ks * 32 + q * 8]);
            f16x8 axl = *(const f16x8*)(&xl_c[n16][ks * 32 + q * 8]);
            f16x8 ahh = *(const f16x8*)(&hh_c[n16][ks * 32 + q * 8]);
#pragma unroll
            for (int g = 0; g < 4; ++g)
#pragma unroll
              for (int cc = 0; cc < 4; ++cc) {
                const int cf = (g * 128 + cc * 32 + w2 * 16 + n16) * 128 + ks * 32 + q * 8;
                f16x8 bh = *(const f16x8*)(Wih + cf);
                f16x8 wh = *(const f16x8*)(Whh + cf);
                acc[g][cc] = mfma16h(axh, bh, acc[g][cc]);
                acc[g][cc] = mfma16h(axl, bh, acc[g][cc]);
                acc[g][cc] = mfma16h(ahh, wh, acc[g][cc]);
              }
          }
        }
        __syncthreads();  // all X/h reads done
        if (act) {
#pragma unroll
          for (int cc = 0; cc < 4; ++cc) {
            int colL = cc * 32 + w2 * 16 + n16;
#pragma unroll
            for (int e = 0; e < 4; ++e) {
              int row = q * 4 + e;
              float gi = acc[0][cc][e] + bgm[0][cc];
              float gf = acc[1][cc][e] + bgm[1][cc];
              float gg = acc[2][cc][e] + bgm[2][cc];
              float go = acc[3][cc][e] + bgm[3][cc];
              float cst = sigm(gf) * creg[e][cc] + sigm(gi) * tanh_f(gg);
              creg[e][cc] = cst;
              float h = sigm(go) * tanh_f(cst);
              hh_c[row][colL] = (f16)h;
              if (s == ns - 1) bcg[(ch * 1024 + b0 + row) * 128 + colL] = h;
            }
          }
        }
      }
      __syncthreads();  // chains done; bcg drained; buffers free
    }

    // ===== decision LSTM: 2 dirs in parallel (256-thread groups) =====
    {
      const int dgr = tid >> 8, dlt = tid & 255, w4 = (tid >> 6) & 3;
      if (tid < 16) {
        int row = tid;
        float v[7], mx = -1e30f;
        for (int j = 0; j < 7; ++j) { v[j] = rcsS[row][9 + j]; mx = fmaxf(mx, v[j]); }
        float s = 0.f;
        for (int j = 0; j < 7; ++j) { v[j] = __expf(v[j] - mx); s += v[j]; }
        float inv = 1.0f / s;
        for (int j = 0; j < 7; ++j) rclD[row][j] = v[j] * inv;
      }
      char* db = smr + dgr * 13056;
      f16 (*xh_d)[136] = (f16 (*)[136])db;
      f16 (*xl_d)[136] = (f16 (*)[136])(db + 4352);
      f16 (*hh_d)[136] = (f16 (*)[136])(db + 8704);
      for (int i = dlt; i < 16 * 136; i += 256) (&hh_d[0][0])[i] = (f16)0.0f;

      const f16* Wih = wAll + WihOffD[dgr];
      const f16* Whh = wAll + WhhOffD[dgr];
      float bgm[4][2];
#pragma unroll
      for (int g = 0; g < 4; ++g)
#pragma unroll
        for (int cc = 0; cc < 2; ++cc)
          bgm[g][cc] = fmisc[bOffD[dgr] + g * 128 + cc * 64 + w4 * 16 + n16];
      float creg[4][2];
#pragma unroll
      for (int e = 0; e < 4; ++e)
#pragma unroll
        for (int cc = 0; cc < 2; ++cc) creg[e][cc] = 0.f;

      const int cold = dlt & 127, rh = dlt >> 7;
      float pfd[8];
      {
        int j0 = dgr ? 6 : 0;
#pragma unroll
        for (int rw = 0; rw < 8; ++rw) {
          int row = rh * 8 + rw;
          pfd[rw] = (j0 < 3) ? usc[(dmk[j0] * 1024 + b0 + row) * 128 + cold]
                             : bcg[((j0 - 3) * 1024 + b0 + row) * 128 + cold];
        }
      }
      __syncthreads();  // rclD + hh zero visible

      for (int s = 0; s < 7; ++s) {
        const int j = dgr ? (6 - s) : s;
        {
#pragma unroll
          for (int rw = 0; rw < 8; ++rw) {
            int row = rh * 8 + rw;
            float xv = rclD[row][j] * pfd[rw];
            f16 xhv = (f16)xv;
            xh_d[row][cold] = xhv;
            xl_d[row][cold] = (f16)(xv - (float)xhv);
          }
          if (s < 6) {
            int j2 = dgr ? (5 - s) : (s + 1);
#pragma unroll
            for (int rw = 0; rw < 8; ++rw) {
              int row = rh * 8 + rw;
              pfd[rw] = (j2 < 3) ? usc[(dmk[j2] * 1024 + b0 + row) * 128 + cold]
                                 : bcg[((j2 - 3) * 1024 + b0 + row) * 128 + cold];
            }
          }
        }
        __syncthreads();
        f32x4 acc[4][2];
        {
          const f32x4 zf = {0.f, 0.f, 0.f, 0.f};
#pragma unroll
          for (int g = 0; g < 4; ++g)
#pragma unroll
            for (int cc = 0; cc < 2; ++cc) acc[g][cc] = zf;
#pragma unroll
          for (int ks = 0; ks < 4; ++ks) {
            f16x8 axh = *(const f16x8*)(&xh_d[n16][ks * 32 + q * 8]);
            f16x8 axl = *(const f16x8*)(&xl_d[n16][ks * 32 + q * 8]);
            f16x8 ahh = *(const f16x8*)(&hh_d[n16][ks * 32 + q * 8]);
#pragma unroll
            for (int g = 0; g < 4; ++g)
#pragma unroll
              for (int cc = 0; cc < 2; ++cc) {
                const int cf = (g * 128 + cc * 64 + w4 * 16 + n16) * 128 + ks * 32 + q * 8;
                f16x8 bh = *(const f16x8*)(Wih + cf);
                f16x8 wh = *(const f16x8*)(Whh + cf);
                acc[g][cc] = mfma16h(axh, bh, acc[g][cc]);
                acc[g][cc] = mfma16h(axl, bh, acc[g][cc]);
                acc[g][cc] = mfma16h(ahh, wh, acc[g][cc]);
              }
          }
        }
        __syncthreads();
        {
#pragma unroll
          for (int cc = 0; cc < 2; ++cc) {
            int colL = cc * 64 + w4 * 16 + n16;
#pragma unroll
            for (int e = 0; e < 4; ++e) {
              int row = q * 4 + e;
              float gi = acc[0][cc][e] + bgm[0][cc];
              float gf = acc[1][cc][e] + bgm[1][cc];
              float gg = acc[2][cc][e] + bgm[2][cc];
              float go = acc[3][cc][e] + bgm[3][cc];
              float cst = sigm(gf) * creg[e][cc] + sigm(gi) * tanh_f(gg);
              creg[e][cc] = cst;
              float h = sigm(go) * tanh_f(cst);
              hh_d[row][colL] = (f16)h;
              if (s == 6) {
                if (dgr == 0) dcF[(b0 + row) * 128 + colL] = h;
                else dcB[(b0 + row) * 128 + colL] = h;
              }
            }
          }
        }
      }
      __syncthreads();  // dirs done; dcF/dcB drained
    }

    // ===== routing update / head =====
    if (r < 3) {
      float newv = 0.f;
      const int row = tid >> 4, cap = tid & 15;
      if (tid < 256) {
        const int goffT[16] = {0, 0, 2, 2, 4, 4, 6, 6, 6, 9, 9, 9, 9, 9, 9, 9};
        const int gnT[16] = {2, 2, 2, 2, 2, 2, 3, 3, 3, 7, 7, 7, 7, 7, 7, 7};
        int go = goffT[cap], gn = gnT[cap];
        float mx = -1e30f;
        for (int j = 0; j < gn; ++j) mx = fmaxf(mx, rcsS[row][go + j]);
        float s = 0.f;
        for (int j = 0; j < gn; ++j) s += __expf(rcsS[row][go + j] - mx);
        float sm = __expf(rcsS[row][cap] - mx) / s;

        const int preMkTab[9] = {0, 4, 1, 8, 5, 9, 2, 6, 10};
        float a = 0.f;
        if (cap < 9) {
          int i = (cap < 6) ? (cap >> 1) : 3;
          const float* pr = usc + (preMkTab[cap] * 1024 + b0 + row) * 128;
          const float* bcrow = bcg + (i * 1024 + b0 + row) * 128;
          for (int dd = 0; dd < 128; ++dd) a += pr[dd] * bcrow[dd];
        } else {
          int j = cap - 9;
          const float* df = dcF + (b0 + row) * 128;
          const float* dbp = dcB + (b0 + row) * 128;
          if (j < 3) {
            const float* pr = usc + (dmk[j] * 1024 + b0 + row) * 128;
            for (int dd = 0; dd < 128; ++dd) a += pr[dd] * (df[dd] + dbp[dd]);
          } else {
            const float* bcrow = bcg + ((j - 3) * 1024 + b0 + row) * 128;
            for (int dd = 0; dd < 128; ++dd) a += bcrow[dd] * (df[dd] + dbp[dd]);
          }
        }
        newv = sm + a;
      }
      __syncthreads();  // all rcsS reads done before in-place update
      if (tid < 256) rcsS[row][cap] = newv;
    } else {
      // head epilogue (order-identical to the old head kernel)
      const int wv = tid >> 6, jj = tid & 63;
#pragma unroll
      for (int pass = 0; pass < 2; ++pass) {
        int row = pass * 8 + wv;
        const float* df = dcF + (b0 + row) * 128;
        const float* dbp = dcB + (b0 + row) * 128;
        float acc = fmisc[209408 + jj];
        for (int dd = 0; dd < 128; ++dd)
          acc += (df[dd] + dbp[dd]) * fmisc[201216 + jj * 128 + dd];
        float o = tanh_f(acc) * fmisc[209472 + jj];
        for (int off = 32; off; off >>= 1) o += __shfl_down(o, off, 64);
        if (jj == 0) {
          float res = o + fmisc[209536];
          if (*flag) ((float*)out)[b0 + row] = res;
          else ((bf16*)out)[b0 + row] = (bf16)res;
        }
      }
    }
  }
}

extern "C" void kernel_launch(void* const* d_in, const int* in_sizes, int n_in,
                              void* d_out, int out_size, void* d_ws, size_t ws_size,
                              hipStream_t stream) {
  float* fw = (float*)d_ws;
  int* flag = (int*)d_ws;
  float* ctx = fw + 4;                  // 393216
  float* usc = ctx + 393216;            // 1572864
  float* dcw = usc + 1572864;           // 131072 (unused)
  float* fmisc = dcw + 131072;          // 209552
  float* rcs = fmisc + 209552;          // 16384 (unused)
  float* bcg = rcs + 16384;             // 524288
  float* dcF = bcg + 524288;            // 131072
  float* dcB = dcF + 131072;            // 131072
  f16* wAll = (f16*)(dcB + 131072);     // 1130496 el

  hipLaunchKernelGGL(detect_dtype, dim3(1), dim3(256), 0, stream,
                     (const unsigned short*)d_in[0], flag);

  PadArgs pa;
  HiloArgs ha;
  for (int m = 0; m < 3; ++m)
    for (int dd = 0; dd < 2; ++dd) {
      int md = m * 6 + dd * 3;
      pa.src[m * 2 + dd] = d_in[3 + md + 0];
      ha.src[m * 2 + dd] = d_in[3 + md + 1];
      ha.n[m * 2 + dd] = 16384;
      ha.off[m * 2 + dd] = 245760 + (m * 2 + dd) * 16384;
    }
  const int hsrc[6] = {24, 25, 27, 28, 30, 31};
  const int hn[6] = {262144, 262144, 65536, 65536, 65536, 65536};
  const int hoff[6] = {344064, 606208, 868352, 933888, 999424, 1064960};
  for (int j = 0; j < 6; ++j) { ha.src[6 + j] = d_in[hsrc[j]]; ha.n[6 + j] = hn[j]; ha.off[6 + j] = hoff[j]; }

  F32Args fa;
  for (int m = 0; m < 3; ++m)
    for (int dd = 0; dd < 2; ++dd) {
      fa.src[m * 2 + dd] = d_in[3 + m * 6 + dd * 3 + 2];
      fa.n[m * 2 + dd] = 256;
      fa.off[m * 2 + dd] = (m * 2 + dd) * 256;
    }
  const int fsrc[10] = {26, 29, 32, 21, 22, 23, 33, 34, 35, 36};
  const int fn[10] = {2048, 512, 512, 65536, 65536, 65536, 8192, 64, 64, 1};
  const int foff[10] = {1536, 3584, 4096, 4608, 70144, 135680, 201216, 209408, 209472, 209536};
  for (int j = 0; j < 10; ++j) { fa.src[6 + j] = d_in[fsrc[j]]; fa.n[6 + j] = fn[j]; fa.off[6 + j] = foff[j]; }

  hipLaunchKernelGGL(conv_all, dim3(64, 34), dim3(256), 0, stream,
                     pa, ha, fa, wAll, fmisc, (const int*)flag);

  TriArgs ta;
  ta.x[0] = d_in[0]; ta.x[1] = d_in[1]; ta.x[2] = d_in[2];
  ta.wAll = wAll; ta.fmisc = fmisc; ta.ctx = ctx; ta.flag = flag;
  hipLaunchKernelGGL(tri_lstm, dim3(384), dim3(512), 0, stream, ta);

  hipLaunchKernelGGL(routing, dim3(64), dim3(512), 0, stream,
                     (const float*)ctx, usc, (const f16*)wAll, (const float*)fmisc,
                     bcg, dcF, dcB, d_out, (const int*)flag);
}

// Round 5
// 803.592 us; speedup vs baseline: 2.5070x; 2.5070x over previous
//
#include <hip/hip_runtime.h>

typedef __bf16 bf16;
typedef _Float16 f16;
typedef f16 f16x8 __attribute__((ext_vector_type(8)));
typedef float f32x4 __attribute__((ext_vector_type(4)));

__device__ __forceinline__ f32x4 mfma16h(f16x8 a, f16x8 b, f32x4 c) {
  return __builtin_amdgcn_mfma_f32_16x16x32_f16(a, b, c, 0, 0, 0);
}
__device__ __forceinline__ float sigm(float x) { return 1.0f / (1.0f + __expf(-x)); }
__device__ __forceinline__ float tanh_f(float x) {
  float e = __expf(-2.0f * fabsf(x));
  return copysignf((1.0f - e) / (1.0f + e), x);
}
__device__ __forceinline__ float ldin(const void* p, long i, int f32m) {
  if (f32m) return ((const float*)p)[i];
  unsigned u = (unsigned)((const unsigned short*)p)[i] << 16;
  return __uint_as_float(u);
}
__device__ __forceinline__ unsigned short f16u(f16 h) { return __builtin_bit_cast(unsigned short, h); }
__device__ __forceinline__ float bfc(unsigned short s) { return __uint_as_float((unsigned)s << 16); }

// ---------------- dtype detection ----------------
__global__ void detect_dtype(const unsigned short* __restrict__ p, int* __restrict__ flag) {
  __shared__ int cnt;
  if (threadIdx.x == 0) cnt = 0;
  __syncthreads();
  int c = 0;
  for (int i = threadIdx.x; i < 4096; i += 256) {
    unsigned e = (p[2 * i] >> 7) & 0xFFu;
    if (e >= 0xC0u) ++c;
  }
  atomicAdd(&cnt, c);
  __syncthreads();
  if (threadIdx.x == 0) *flag = (cnt > 64) ? 1 : 0;
}

// ---------------- converters: all weights -> single fp16 (one kernel) ----------------
// wAll (f16) element offsets:
//   padded tri Wih: table below                    total 245760
//   tri Whh: 245760 + md*16384                     total 98304
//   r_Wih: 344064 + c*65536   r_Whh: 606208 + c*65536
//   dWihF: 868352  dWhhF: 933888  dWihB: 999424  dWhhB: 1064960   end 1130496
// fmisc float offsets: tri bias md*256; r_b 1536; d_b_f 3584; d_b_b 4096;
//   uscW 4608+mk*16384; fc1W 201216; fc1b 209408; fc2W 209472; fc2b 209536

struct PadArgs { const void* src[6]; };
struct HiloArgs { const void* src[12]; int n[12]; int off[12]; };
struct F32Args { const void* src[16]; int n[16]; int off[16]; };

__global__ void conv_all(PadArgs pa, HiloArgs ha, F32Args fa,
                         f16* __restrict__ wo, float* __restrict__ fm,
                         const int* __restrict__ flag) {
  const int y = blockIdx.y;
  const int f32m = *flag;
  if (y < 6) {
    const int dinT[6] = {300, 300, 74, 74, 35, 35};
    const int kpT[6] = {320, 320, 96, 96, 64, 64};
    const int offT[6] = {0, 81920, 163840, 188416, 212992, 229376};
    int din = dinT[y], kp = kpT[y];
    const void* s = pa.src[y];
    f16* o = wo + offT[y];
    int total = 256 * kp;
    for (int i = blockIdx.x * blockDim.x + threadIdx.x; i < total; i += gridDim.x * blockDim.x) {
      int n = i / kp, k = i - n * kp;
      float v = (k < din) ? ldin(s, n * din + k, f32m) : 0.0f;
      o[i] = (f16)v;
    }
  } else if (y < 18) {
    int j = y - 6;
    int n = ha.n[j];
    const void* s = ha.src[j];
    f16* o = wo + ha.off[j];
    for (int i = blockIdx.x * blockDim.x + threadIdx.x; i < n; i += gridDim.x * blockDim.x)
      o[i] = (f16)ldin(s, i, f32m);
  } else {
    int j = y - 18;
    int n = fa.n[j];
    const void* s = fa.src[j];
    float* d = fm + fa.off[j];
    for (int i = blockIdx.x * blockDim.x + threadIdx.x; i < n; i += gridDim.x * blockDim.x)
      d[i] = ldin(s, i, f32m);
  }
}

__global__ void init_rc(float* __restrict__ rcs) {
  int i = blockIdx.x * 256 + threadIdx.x;
  if (i < 16384) rcs[i] = 1.0f;
}

// ---------------- fused trimodal bidirectional LSTMs (fp16 MFMA) ----------------
struct TriArgs {
  const void* x[3];
  const f16* wAll;
  const float* fmisc;
  float* ctx;
  const int* flag;
};

// 512 threads = 8 waves, register-resident weights, all-wave gate math.
// (R2-proven version, 365 us, bit-identical output.)
template <int DIN, int KP, int CHUNK, int F32M>
__device__ void tri_body(const void* __restrict__ xsrc,
                         const f16* __restrict__ wp, const f16* __restrict__ whh,
                         const float* __restrict__ bias, float* __restrict__ ctx,
                         int m, int d, int b0, char* sm) {
  constexpr int XP = KP + 8;
  constexpr int NKS = KP / 32;
  constexpr int NCH = DIN / CHUNK;
  constexpr int ITER = (NCH + 15) / 16;

  f16 (*Xhi)[XP] = (f16 (*)[XP])sm;
  f16 (*Xlo)[XP] = (f16 (*)[XP])(sm + 32 * XP * 2);
  f16 (*hbuf)[16][72] = (f16 (*)[16][72])(sm + 64 * XP * 2);
  float* gbuf = (float*)(sm + 64 * XP * 2 + 4608);  // [16][260] f32

  const int tid = threadIdx.x;
  const int lane = tid & 63, n16 = lane & 15, q = lane >> 4, w8 = tid >> 6;
  const int srow = tid & 31, sct = tid >> 5;
  const int hc = tid & 63, rr = tid >> 6;

  f16x8 wihr[2][NKS];
  f16x8 whr[2][2];
#pragma unroll
  for (int t = 0; t < 2; ++t) {
    int cc = (w8 + t * 8) * 16 + n16;
#pragma unroll
    for (int ks = 0; ks < NKS; ++ks)
      wihr[t][ks] = *(const f16x8*)(wp + cc * KP + ks * 32 + q * 8);
#pragma unroll
    for (int ks = 0; ks < 2; ++ks)
      whr[t][ks] = *(const f16x8*)(whh + cc * 64 + ks * 32 + q * 8);
  }
  float bgm[4];
#pragma unroll
  for (int g = 0; g < 4; ++g) bgm[g] = bias[g * 64 + hc];

  {
    unsigned* z = (unsigned*)sm;
    int nz = (64 * XP * 2 + 4608) >> 2;
    for (int i = tid; i < nz; i += 512) z[i] = 0u;
  }

  uint4 pf[ITER];
  auto stage_load = [&](int tg) {
#pragma unroll
    for (int i = 0; i < ITER; ++i) {
      int c = sct + i * 16;
      if (c < NCH) {
        int tl = srow >> 4, bb = srow & 15;
        int t = tg * 2 + tl; if (d) t = 127 - t;
        long base = ((long)(b0 + bb) * 128 + t) * DIN + c * CHUNK;
        if (F32M) {
          const float* p = (const float*)xsrc + base;
          if constexpr (CHUNK == 4) pf[i] = *(const uint4*)p;
          else if constexpr (CHUNK == 2) { uint2 v = *(const uint2*)p; pf[i].x = v.x; pf[i].y = v.y; }
          else pf[i].x = *(const unsigned*)p;
        } else {
          const unsigned short* p = (const unsigned short*)xsrc + base;
          if constexpr (CHUNK == 4) { uint2 v = *(const uint2*)p; pf[i].x = v.x; pf[i].y = v.y; }
          else if constexpr (CHUNK == 2) pf[i].x = *(const unsigned*)p;
          else pf[i].x = *p;
        }
      }
    }
  };
  auto stage_store = [&]() {
#pragma unroll
    for (int i = 0; i < ITER; ++i) {
      int c = sct + i * 16;
      if (c < NCH) {
        float v[4];
        if (F32M) {
          v[0] = __uint_as_float(pf[i].x); v[1] = __uint_as_float(pf[i].y);
          v[2] = __uint_as_float(pf[i].z); v[3] = __uint_as_float(pf[i].w);
        } else {
          v[0] = bfc((unsigned short)(pf[i].x & 0xFFFF));
          v[1] = bfc((unsigned short)(pf[i].x >> 16));
          v[2] = bfc((unsigned short)(pf[i].y & 0xFFFF));
          v[3] = bfc((unsigned short)(pf[i].y >> 16));
        }
        unsigned short hb[4], lb[4];
#pragma unroll
        for (int e = 0; e < CHUNK; ++e) {
          f16 h = (f16)v[e];
          hb[e] = f16u(h);
          lb[e] = f16u((f16)(v[e] - (float)h));
        }
        if constexpr (CHUNK == 4) {
          uint2 H; H.x = hb[0] | ((unsigned)hb[1] << 16); H.y = hb[2] | ((unsigned)hb[3] << 16);
          *(uint2*)&Xhi[srow][c * 4] = H;
          if (F32M) {
            uint2 L; L.x = lb[0] | ((unsigned)lb[1] << 16); L.y = lb[2] | ((unsigned)lb[3] << 16);
            *(uint2*)&Xlo[srow][c * 4] = L;
          }
        } else if constexpr (CHUNK == 2) {
          *(unsigned*)&Xhi[srow][c * 2] = hb[0] | ((unsigned)hb[1] << 16);
          if (F32M) *(unsigned*)&Xlo[srow][c * 2] = lb[0] | ((unsigned)lb[1] << 16);
        } else {
          *(unsigned short*)&Xhi[srow][c] = hb[0];
          if (F32M) *(unsigned short*)&Xlo[srow][c] = lb[0];
        }
      }
    }
  };

  float c2[2] = {0.f, 0.f};
  stage_load(0);
  __syncthreads();

  for (int tg = 0; tg < 64; ++tg) {
    stage_store();
    if (tg < 63) stage_load(tg + 1);
    __syncthreads();

    f32x4 a00, a01, a10, a11;
    {
      const f32x4 zf = {0.f, 0.f, 0.f, 0.f};
      a00 = zf; a01 = zf; a10 = zf; a11 = zf;
    }
#pragma unroll
    for (int ks = 0; ks < NKS; ++ks) {
      f16x8 ah0 = *(const f16x8*)(&Xhi[n16][ks * 32 + q * 8]);
      f16x8 ah1 = *(const f16x8*)(&Xhi[16 + n16][ks * 32 + q * 8]);
      a00 = mfma16h(ah0, wihr[0][ks], a00);
      a01 = mfma16h(ah0, wihr[1][ks], a01);
      a10 = mfma16h(ah1, wihr[0][ks], a10);
      a11 = mfma16h(ah1, wihr[1][ks], a11);
      if (F32M) {
        f16x8 al0 = *(const f16x8*)(&Xlo[n16][ks * 32 + q * 8]);
        f16x8 al1 = *(const f16x8*)(&Xlo[16 + n16][ks * 32 + q * 8]);
        a00 = mfma16h(al0, wihr[0][ks], a00);
        a01 = mfma16h(al0, wihr[1][ks], a01);
        a10 = mfma16h(al1, wihr[0][ks], a10);
        a11 = mfma16h(al1, wihr[1][ks], a11);
      }
    }

    {
      f16x8 h0 = *(const f16x8*)(&hbuf[0][n16][q * 8]);
      f16x8 h1 = *(const f16x8*)(&hbuf[0][n16][32 + q * 8]);
      a00 = mfma16h(h0, whr[0][0], a00); a00 = mfma16h(h1, whr[0][1], a00);
      a01 = mfma16h(h0, whr[1][0], a01); a01 = mfma16h(h1, whr[1][1], a01);
    }
#pragma unroll
    for (int e = 0; e < 4; ++e) {
      gbuf[(q * 4 + e) * 260 + w8 * 16 + n16] = a00[e];
      gbuf[(q * 4 + e) * 260 + 128 + w8 * 16 + n16] = a01[e];
    }
    __syncthreads();

#pragma unroll
    for (int e = 0; e < 2; ++e) {
      int row = rr + e * 8;
      float gi = gbuf[row * 260 + hc] + bgm[0];
      float gf = gbuf[row * 260 + 64 + hc] + bgm[1];
      float gg = gbuf[row * 260 + 128 + hc] + bgm[2];
      float go = gbuf[row * 260 + 192 + hc] + bgm[3];
      float c = sigm(gf) * c2[e] + sigm(gi) * tanh_f(gg);
      c2[e] = c;
      float h = sigm(go) * tanh_f(c);
      hbuf[1][row][hc] = (f16)h;
    }
    __syncthreads();

    {
      f16x8 h0 = *(const f16x8*)(&hbuf[1][n16][q * 8]);
      f16x8 h1 = *(const f16x8*)(&hbuf[1][n16][32 + q * 8]);
      a10 = mfma16h(h0, whr[0][0], a10); a10 = mfma16h(h1, whr[0][1], a10);
      a11 = mfma16h(h0, whr[1][0], a11); a11 = mfma16h(h1, whr[1][1], a11);
    }
#pragma unroll
    for (int e = 0; e < 4; ++e) {
      gbuf[(q * 4 + e) * 260 + w8 * 16 + n16] = a10[e];
      gbuf[(q * 4 + e) * 260 + 128 + w8 * 16 + n16] = a11[e];
    }
    __syncthreads();

    const bool lastStep = (tg == 63);
#pragma unroll
    for (int e = 0; e < 2; ++e) {
      int row = rr + e * 8;
      float gi = gbuf[row * 260 + hc] + bgm[0];
      float gf = gbuf[row * 260 + 64 + hc] + bgm[1];
      float gg = gbuf[row * 260 + 128 + hc] + bgm[2];
      float go = gbuf[row * 260 + 192 + hc] + bgm[3];
      float c = sigm(gf) * c2[e] + sigm(gi) * tanh_f(gg);
      c2[e] = c;
      float h = sigm(go) * tanh_f(c);
      hbuf[0][row][hc] = (f16)h;
      if (lastStep) ctx[(m * 1024 + b0 + row) * 128 + d * 64 + hc] = h;
    }
  }
}

__global__ __launch_bounds__(512, 2) void tri_lstm(TriArgs A) {
  __shared__ __align__(16) char sm[64 * 328 * 2 + 4608 + 16640];
  int bid = blockIdx.x;
  int md = bid >> 6, xb = bid & 63;
  int m = md >> 1, d = md & 1, b0 = xb * 16;
  const int wpOffT[6] = {0, 81920, 163840, 188416, 212992, 229376};
  const f16* wp = A.wAll + wpOffT[md];
  const f16* whh = A.wAll + 245760 + md * 16384;
  const float* bias = A.fmisc + md * 256;
  int f32m = *A.flag;
  if (f32m) {
    if (m == 0)      tri_body<300, 320, 4, 1>(A.x[0], wp, whh, bias, A.ctx, m, d, b0, sm);
    else if (m == 1) tri_body<74, 96, 2, 1>(A.x[1], wp, whh, bias, A.ctx, m, d, b0, sm);
    else             tri_body<35, 64, 1, 1>(A.x[2], wp, whh, bias, A.ctx, m, d, b0, sm);
  } else {
    if (m == 0)      tri_body<300, 320, 4, 0>(A.x[0], wp, whh, bias, A.ctx, m, d, b0, sm);
    else if (m == 1) tri_body<74, 96, 2, 0>(A.x[1], wp, whh, bias, A.ctx, m, d, b0, sm);
    else             tri_body<35, 64, 1, 0>(A.x[2], wp, whh, bias, A.ctx, m, d, b0, sm);
  }
}

// ---------------- usc einsum (4 rows/block for W reuse) ----------------
__global__ __launch_bounds__(128) void usc_kern(const float* __restrict__ ctx,
                                                const float* __restrict__ fmisc,
                                                float* __restrict__ usc) {
  __shared__ float cr[4][128];
  int b0 = blockIdx.x * 4;
  int mk = blockIdx.y, mod = mk >> 2;
  int e = threadIdx.x;
  const float* W = fmisc + 4608 + mk * 16384;
  for (int i = e; i < 512; i += 128) {
    int r = i >> 7, dd = i & 127;
    cr[r][dd] = ctx[(mod * 1024 + b0 + r) * 128 + dd];
  }
  __syncthreads();
  float a0 = 0.f, a1 = 0.f, a2 = 0.f, a3 = 0.f;
  for (int dd = 0; dd < 128; ++dd) {
    float wv = W[dd * 128 + e];
    a0 += cr[0][dd] * wv; a1 += cr[1][dd] * wv;
    a2 += cr[2][dd] * wv; a3 += cr[3][dd] * wv;
  }
  usc[(mk * 1024 + b0 + 0) * 128 + e] = a0;
  usc[(mk * 1024 + b0 + 1) * 128 + e] = a1;
  usc[(mk * 1024 + b0 + 2) * 128 + e] = a2;
  usc[(mk * 1024 + b0 + 3) * 128 + e] = a3;
}

// ---------------- routing phase kernels (fp16 MFMA) ----------------
// Both weight sets register-resident (bhf=Wih, whf=Whh); staging inputs
// prefetched one step ahead. MFMA order per output element unchanged.
#define LSTM_STEP_DECL \
  const int tid = threadIdx.x; \
  const int lane = tid & 63, n16 = lane & 15, q = lane >> 4, w = tid >> 6; \
  const int u = w * 16 + n16; \
  const int u2 = tid & 127, rgg = tid >> 7;

__device__ __forceinline__ void lstm_step_mfma_r(
    f32x4* acc, const f16 (*xh)[16][136], const f16 (*xl)[16][136],
    const f16 (*hh)[16][136], int p,
    const f16x8 (*bhf)[4], const f16x8 (*whf)[4],
    int n16, int q) {
#pragma unroll
  for (int ks = 0; ks < 4; ++ks) {
    f16x8 axh = *(const f16x8*)(&xh[p][n16][ks * 32 + q * 8]);
    f16x8 axl = *(const f16x8*)(&xl[p][n16][ks * 32 + q * 8]);
    f16x8 ahh = *(const f16x8*)(&hh[p][n16][ks * 32 + q * 8]);
#pragma unroll
    for (int g = 0; g < 4; ++g) {
      acc[g] = mfma16h(axh, bhf[g][ks], acc[g]);
      acc[g] = mfma16h(axl, bhf[g][ks], acc[g]);
      acc[g] = mfma16h(ahh, whf[g][ks], acc[g]);
    }
  }
}

__global__ __launch_bounds__(512) void rchain(const float* __restrict__ usc,
                                              const float* __restrict__ rcs,
                                              const f16* __restrict__ wAll,
                                              const float* __restrict__ fmisc,
                                              float* __restrict__ bcg) {
  __shared__ __align__(16) f16 xh[2][16][136], xl[2][16][136], hh[2][16][136];
  __shared__ float rcl[16][3];
  LSTM_STEP_DECL
  const int chain = blockIdx.y;
  const int b0 = blockIdx.x * 16;
  const int WihOff[4] = {344064, 409600, 475136, 540672};
  const int WhhOff[4] = {606208, 671744, 737280, 802816};
  const int bOff[4] = {1536, 2048, 2560, 3072};
  const int ns = (chain == 3) ? 3 : 2;

  if (tid < 16) {
    int row = tid;
    int goff = (chain == 3) ? 6 : chain * 2;
    float v[3], mx = -1e30f;
    for (int j = 0; j < ns; ++j) { v[j] = rcs[(b0 + row) * 16 + goff + j]; mx = fmaxf(mx, v[j]); }
    float s = 0.f;
    for (int j = 0; j < ns; ++j) { v[j] = __expf(v[j] - mx); s += v[j]; }
    float inv = 1.0f / s;
    for (int j = 0; j < ns; ++j) rcl[row][j] = v[j] * inv;
  }
  for (int i = tid; i < 2 * 16 * 136; i += 512) (&hh[0][0][0])[i] = (f16)0.0f;

  const f16* Whh = wAll + WhhOff[chain];
  const f16* Wih = wAll + WihOff[chain];
  f16x8 whf[4][4], bhf[4][4];
#pragma unroll
  for (int g = 0; g < 4; ++g)
#pragma unroll
    for (int ks = 0; ks < 4; ++ks) {
      whf[g][ks] = *(const f16x8*)(Whh + (g * 128 + u) * 128 + ks * 32 + q * 8);
      bhf[g][ks] = *(const f16x8*)(Wih + (g * 128 + u) * 128 + ks * 32 + q * 8);
    }
  const float* bias = fmisc + bOff[chain];
  float bg[4];
#pragma unroll
  for (int g = 0; g < 4; ++g) bg[g] = bias[g * 128 + u];

  const int preMk0[4] = {0, 1, 5, 2};
  const int preMk1[4] = {4, 8, 9, 6};
  float creg[4] = {0.f, 0.f, 0.f, 0.f};

  float pv[4];
  {
    int mk0 = preMk0[chain];
#pragma unroll
    for (int rr = 0; rr < 4; ++rr)
      pv[rr] = usc[(mk0 * 1024 + b0 + rgg * 4 + rr) * 128 + u2];
  }
  __syncthreads();

  for (int s = 0; s < ns; ++s) {
    int p = s & 1;
#pragma unroll
    for (int rr = 0; rr < 4; ++rr) {
      int row = rgg * 4 + rr;
      float xv = rcl[row][s] * pv[rr];
      f16 xhv = (f16)xv;
      xh[p][row][u2] = xhv;
      xl[p][row][u2] = (f16)(xv - (float)xhv);
    }
    if (s + 1 < ns) {
      int mk2 = (s + 1 == 1) ? preMk1[chain] : 10;
#pragma unroll
      for (int rr = 0; rr < 4; ++rr)
        pv[rr] = usc[(mk2 * 1024 + b0 + rgg * 4 + rr) * 128 + u2];
    }
    __syncthreads();
    f32x4 acc[4];
    const f32x4 zf = {0.f, 0.f, 0.f, 0.f};
#pragma unroll
    for (int g = 0; g < 4; ++g) acc[g] = zf;
    lstm_step_mfma_r(acc, xh, xl, hh, p, bhf, whf, n16, q);
#pragma unroll
    for (int e = 0; e < 4; ++e) {
      int row = q * 4 + e;
      float gi = acc[0][e] + bg[0];
      float gf = acc[1][e] + bg[1];
      float gg = acc[2][e] + bg[2];
      float go = acc[3][e] + bg[3];
      float c = sigm(gf) * creg[e] + sigm(gi) * tanh_f(gg);
      creg[e] = c;
      float h = sigm(go) * tanh_f(c);
      hh[p ^ 1][row][u] = (f16)h;
      if (s == ns - 1) bcg[(chain * 1024 + b0 + row) * 128 + u] = h;
    }
  }
}

__global__ __launch_bounds__(512) void decision(const float* __restrict__ usc,
                                                const float* __restrict__ rcs,
                                                const f16* __restrict__ wAll,
                                                const float* __restrict__ fmisc,
                                                const float* __restrict__ bcg,
                                                float* __restrict__ dcF,
                                                float* __restrict__ dcB) {
  __shared__ __align__(16) f16 xh[2][16][136], xl[2][16][136], hh[2][16][136];
  __shared__ float rcl[16][7];
  LSTM_STEP_DECL
  const int dir = blockIdx.y;
  const int b0 = blockIdx.x * 16;

  if (tid < 16) {
    int row = tid;
    float v[7], mx = -1e30f;
    for (int j = 0; j < 7; ++j) { v[j] = rcs[(b0 + row) * 16 + 9 + j]; mx = fmaxf(mx, v[j]); }
    float s = 0.f;
    for (int j = 0; j < 7; ++j) { v[j] = __expf(v[j] - mx); s += v[j]; }
    float inv = 1.0f / s;
    for (int j = 0; j < 7; ++j) rcl[row][j] = v[j] * inv;
  }
  for (int i = tid; i < 2 * 16 * 136; i += 512) (&hh[0][0][0])[i] = (f16)0.0f;

  const int WihOffD[2] = {868352, 999424};
  const int WhhOffD[2] = {933888, 1064960};
  const int bOffD[2] = {3584, 4096};
  const f16* Whh = wAll + WhhOffD[dir];
  const f16* Wih = wAll + WihOffD[dir];
  f16x8 whf[4][4], bhf[4][4];
#pragma unroll
  for (int g = 0; g < 4; ++g)
#pragma unroll
    for (int ks = 0; ks < 4; ++ks) {
      whf[g][ks] = *(const f16x8*)(Whh + (g * 128 + u) * 128 + ks * 32 + q * 8);
      bhf[g][ks] = *(const f16x8*)(Wih + (g * 128 + u) * 128 + ks * 32 + q * 8);
    }
  const float* bias = fmisc + bOffD[dir];
  float bg[4];
#pragma unroll
  for (int g = 0; g < 4; ++g) bg[g] = bias[g * 128 + u];

  const int dmk[3] = {3, 7, 11};
  float creg[4] = {0.f, 0.f, 0.f, 0.f};

  float pv[4];
  {
    int j0 = dir ? 6 : 0;
#pragma unroll
    for (int rr = 0; rr < 4; ++rr) {
      int row = rgg * 4 + rr;
      pv[rr] = (j0 < 3) ? usc[(dmk[j0] * 1024 + b0 + row) * 128 + u2]
                        : bcg[((j0 - 3) * 1024 + b0 + row) * 128 + u2];
    }
  }
  __syncthreads();

  for (int s = 0; s < 7; ++s) {
    int p = s & 1;
    int j = dir ? (6 - s) : s;
#pragma unroll
    for (int rr = 0; rr < 4; ++rr) {
      int row = rgg * 4 + rr;
      float xv = rcl[row][j] * pv[rr];
      f16 xhv = (f16)xv;
      xh[p][row][u2] = xhv;
      xl[p][row][u2] = (f16)(xv - (float)xhv);
    }
    if (s < 6) {
      int j2 = dir ? (5 - s) : (s + 1);
#pragma unroll
      for (int rr = 0; rr < 4; ++rr) {
        int row = rgg * 4 + rr;
        pv[rr] = (j2 < 3) ? usc[(dmk[j2] * 1024 + b0 + row) * 128 + u2]
                          : bcg[((j2 - 3) * 1024 + b0 + row) * 128 + u2];
      }
    }
    __syncthreads();
    f32x4 acc[4];
    const f32x4 zf = {0.f, 0.f, 0.f, 0.f};
#pragma unroll
    for (int g = 0; g < 4; ++g) acc[g] = zf;
    lstm_step_mfma_r(acc, xh, xl, hh, p, bhf, whf, n16, q);
#pragma unroll
    for (int e = 0; e < 4; ++e) {
      int row = q * 4 + e;
      float gi = acc[0][e] + bg[0];
      float gf = acc[1][e] + bg[1];
      float gg = acc[2][e] + bg[2];
      float go = acc[3][e] + bg[3];
      float c = sigm(gf) * creg[e] + sigm(gi) * tanh_f(gg);
      creg[e] = c;
      float h = sigm(go) * tanh_f(c);
      hh[p ^ 1][row][u] = (f16)h;
      if (s == 6) {
        if (dir == 0) dcF[(b0 + row) * 128 + u] = h;
        else dcB[(b0 + row) * 128 + u] = h;
      }
    }
  }
}

__global__ __launch_bounds__(256) void rupdate(const float* __restrict__ usc,
                                               const float* __restrict__ bcg,
                                               const float* __restrict__ dcF,
                                               const float* __restrict__ dcB,
                                               float* __restrict__ rcs,
                                               float* __restrict__ dcw, int last) {
  __shared__ float dsum[16][128];
  __shared__ float rcl[16][16];
  const int tid = threadIdx.x;
  const int b0 = blockIdx.x * 16;
  for (int i = tid; i < 2048; i += 256) {
    int row = i >> 7, col = i & 127;
    float v = dcF[(b0 + row) * 128 + col] + dcB[(b0 + row) * 128 + col];
    dsum[row][col] = v;
    if (last) dcw[(b0 + row) * 128 + col] = v;
  }
  {
    int row = tid >> 4, cap = tid & 15;
    rcl[row][cap] = rcs[(b0 + row) * 16 + cap];
  }
  __syncthreads();
  if (!last) {
    int row = tid >> 4, cap = tid & 15;
    const int goffT[16] = {0, 0, 2, 2, 4, 4, 6, 6, 6, 9, 9, 9, 9, 9, 9, 9};
    const int gnT[16] = {2, 2, 2, 2, 2, 2, 3, 3, 3, 7, 7, 7, 7, 7, 7, 7};
    int go = goffT[cap], gn = gnT[cap];
    float mx = -1e30f;
    for (int j = 0; j < gn; ++j) mx = fmaxf(mx, rcl[row][go + j]);
    float s = 0.f;
    for (int j = 0; j < gn; ++j) s += __expf(rcl[row][go + j] - mx);
    float sm = __expf(rcl[row][cap] - mx) / s;

    const int preMkTab[9] = {0, 4, 1, 8, 5, 9, 2, 6, 10};
    float a = 0.f;
    if (cap < 9) {
      int i = (cap < 6) ? (cap >> 1) : 3;
      const float* pr = usc + (preMkTab[cap] * 1024 + b0 + row) * 128;
      const float* bcrow = bcg + (i * 1024 + b0 + row) * 128;
      for (int dd = 0; dd < 128; ++dd) a += pr[dd] * bcrow[dd];
    } else {
      int j = cap - 9;
      if (j < 3) {
        const int dmk[3] = {3, 7, 11};
        const float* pr = usc + (dmk[j] * 1024 + b0 + row) * 128;
        for (int dd = 0; dd < 128; ++dd) a += pr[dd] * dsum[row][dd];
      } else {
        const float* bcrow = bcg + ((j - 3) * 1024 + b0 + row) * 128;
        for (int dd = 0; dd < 128; ++dd) a += bcrow[dd] * dsum[row][dd];
      }
    }
    rcs[(b0 + row) * 16 + cap] = sm + a;
  }
}

// ---------------- head ----------------
__global__ __launch_bounds__(64) void head(const float* __restrict__ dc, const float* __restrict__ fcw,
                                           void* __restrict__ out, const int* __restrict__ flag) {
  int b = blockIdx.x, j = threadIdx.x;
  const float* r = dc + b * 128;
  float acc = fcw[209408 + j];
  for (int dd = 0; dd < 128; ++dd) acc += r[dd] * fcw[201216 + j * 128 + dd];
  float o = tanh_f(acc) * fcw[209472 + j];
  for (int off = 32; off; off >>= 1) o += __shfl_down(o, off, 64);
  if (j == 0) {
    float res = o + fcw[209536];
    if (*flag) ((float*)out)[b] = res;
    else ((bf16*)out)[b] = (bf16)res;
  }
}

extern "C" void kernel_launch(void* const* d_in, const int* in_sizes, int n_in,
                              void* d_out, int out_size, void* d_ws, size_t ws_size,
                              hipStream_t stream) {
  float* fw = (float*)d_ws;
  int* flag = (int*)d_ws;
  float* ctx = fw + 4;                  // 393216
  float* usc = ctx + 393216;            // 1572864
  float* dcw = usc + 1572864;           // 131072
  float* fmisc = dcw + 131072;          // 209552
  float* rcs = fmisc + 209552;          // 16384
  float* bcg = rcs + 16384;             // 524288
  float* dcF = bcg + 524288;            // 131072
  float* dcB = dcF + 131072;            // 131072
  f16* wAll = (f16*)(dcB + 131072);     // 1130496 el

  hipLaunchKernelGGL(detect_dtype, dim3(1), dim3(256), 0, stream,
                     (const unsigned short*)d_in[0], flag);

  PadArgs pa;
  HiloArgs ha;
  for (int m = 0; m < 3; ++m)
    for (int dd = 0; dd < 2; ++dd) {
      int md = m * 6 + dd * 3;
      pa.src[m * 2 + dd] = d_in[3 + md + 0];
      ha.src[m * 2 + dd] = d_in[3 + md + 1];
      ha.n[m * 2 + dd] = 16384;
      ha.off[m * 2 + dd] = 245760 + (m * 2 + dd) * 16384;
    }
  const int hsrc[6] = {24, 25, 27, 28, 30, 31};
  const int hn[6] = {262144, 262144, 65536, 65536, 65536, 65536};
  const int hoff[6] = {344064, 606208, 868352, 933888, 999424, 1064960};
  for (int j = 0; j < 6; ++j) { ha.src[6 + j] = d_in[hsrc[j]]; ha.n[6 + j] = hn[j]; ha.off[6 + j] = hoff[j]; }

  F32Args fa;
  for (int m = 0; m < 3; ++m)
    for (int dd = 0; dd < 2; ++dd) {
      fa.src[m * 2 + dd] = d_in[3 + m * 6 + dd * 3 + 2];
      fa.n[m * 2 + dd] = 256;
      fa.off[m * 2 + dd] = (m * 2 + dd) * 256;
    }
  const int fsrc[10] = {26, 29, 32, 21, 22, 23, 33, 34, 35, 36};
  const int fn[10] = {2048, 512, 512, 65536, 65536, 65536, 8192, 64, 64, 1};
  const int foff[10] = {1536, 3584, 4096, 4608, 70144, 135680, 201216, 209408, 209472, 209536};
  for (int j = 0; j < 10; ++j) { fa.src[6 + j] = d_in[fsrc[j]]; fa.n[6 + j] = fn[j]; fa.off[6 + j] = foff[j]; }

  hipLaunchKernelGGL(conv_all, dim3(64, 34), dim3(256), 0, stream,
                     pa, ha, fa, wAll, fmisc, (const int*)flag);
  hipLaunchKernelGGL(init_rc, dim3(64), dim3(256), 0, stream, rcs);

  TriArgs ta;
  ta.x[0] = d_in[0]; ta.x[1] = d_in[1]; ta.x[2] = d_in[2];
  ta.wAll = wAll; ta.fmisc = fmisc; ta.ctx = ctx; ta.flag = flag;
  hipLaunchKernelGGL(tri_lstm, dim3(384), dim3(512), 0, stream, ta);

  hipLaunchKernelGGL(usc_kern, dim3(256, 12), dim3(128), 0, stream,
                     (const float*)ctx, (const float*)fmisc, usc);

  for (int r = 0; r < 4; ++r) {
    hipLaunchKernelGGL(rchain, dim3(64, 4), dim3(512), 0, stream,
                       (const float*)usc, (const float*)rcs, (const f16*)wAll,
                       (const float*)fmisc, bcg);
    hipLaunchKernelGGL(decision, dim3(64, 2), dim3(512), 0, stream,
                       (const float*)usc, (const float*)rcs, (const f16*)wAll,
                       (const float*)fmisc, (const float*)bcg, dcF, dcB);
    hipLaunchKernelGGL(rupdate, dim3(64), dim3(256), 0, stream,
                       (const float*)usc, (const float*)bcg, (const float*)dcF,
                       (const float*)dcB, rcs, dcw, (r == 3) ? 1 : 0);
  }

  hipLaunchKernelGGL(head, dim3(1024), dim3(64), 0, stream,
                     (const float*)dcw, (const float*)fmisc, d_out, (const int*)flag);
}